// Round 5
// baseline (534.858 us; speedup 1.0000x reference)
//
#include <hip/hip_runtime.h>
#include <math.h>

#define NB 16
#define DKC 512
#define NP 2048
#define BN 128
#define BM 128
#define BK 64
#define NSTEP 64   // 8 m-pairs x 8 k-chunks

typedef __attribute__((ext_vector_type(8))) short sh8;
typedef __attribute__((ext_vector_type(4))) float f32x4;

// ---------------------------------------------------------------------------
// Device-side Kabsch from the 15 per-batch moments (double Jacobi of H^T H).
// ---------------------------------------------------------------------------
__device__ void kabsch_body(const double* a, float* out, int b)
{
    const double invN = 1.0 / NP;
    const double mus[3] = { a[0] * invN, a[1] * invN, a[2] * invN };
    const double muc[3] = { a[3] * invN, a[4] * invN, a[5] * invN };
    double Hm[3][3];
    for (int i = 0; i < 3; ++i)
        for (int j = 0; j < 3; ++j)
            Hm[i][j] = a[6 + i * 3 + j] - (double)NP * mus[i] * muc[j];

    double A[3][3], V[3][3] = { {1,0,0},{0,1,0},{0,0,1} };
    for (int i = 0; i < 3; ++i)
        for (int j = 0; j < 3; ++j) {
            double s = 0;
            for (int k = 0; k < 3; ++k) s += Hm[k][i] * Hm[k][j];
            A[i][j] = s;
        }
    const int PP[3] = { 0, 0, 1 }, QQ[3] = { 1, 2, 2 };
    for (int sweep = 0; sweep < 12; ++sweep) {
        for (int r = 0; r < 3; ++r) {
            const int p = PP[r], q = QQ[r];
            const double apq = A[p][q];
            if (apq * apq <= 1e-32 * A[p][p] * A[q][q]) continue;
            const double theta = (A[q][q] - A[p][p]) / (2.0 * apq);
            const double tt = (theta >= 0 ? 1.0 : -1.0) / (fabs(theta) + sqrt(1.0 + theta * theta));
            const double c = 1.0 / sqrt(1.0 + tt * tt);
            const double s = tt * c;
            for (int k = 0; k < 3; ++k) {
                const double akp = A[k][p], akq = A[k][q];
                A[k][p] = c * akp - s * akq;
                A[k][q] = s * akp + c * akq;
            }
            for (int k = 0; k < 3; ++k) {
                const double apk = A[p][k], aqk = A[q][k];
                A[p][k] = c * apk - s * aqk;
                A[q][k] = s * apk + c * aqk;
            }
            for (int k = 0; k < 3; ++k) {
                const double vkp = V[k][p], vkq = V[k][q];
                V[k][p] = c * vkp - s * vkq;
                V[k][q] = s * vkp + c * vkq;
            }
        }
    }
    int idx[3] = { 0, 1, 2 };
    for (int i = 0; i < 2; ++i)
        for (int j = i + 1; j < 3; ++j)
            if (A[idx[j]][idx[j]] > A[idx[i]][idx[i]]) { const int t = idx[i]; idx[i] = idx[j]; idx[j] = t; }
    double Vs[3][3], U[3][3];
    for (int j = 0; j < 3; ++j)
        for (int i = 0; i < 3; ++i) Vs[i][j] = V[i][idx[j]];
    for (int j = 0; j < 3; ++j) {
        double hv[3] = { 0, 0, 0 };
        for (int i = 0; i < 3; ++i)
            for (int k = 0; k < 3; ++k) hv[i] += Hm[i][k] * Vs[k][j];
        double s = sqrt(hv[0] * hv[0] + hv[1] * hv[1] + hv[2] * hv[2]);
        s = fmax(s, 1e-300);
        for (int i = 0; i < 3; ++i) U[i][j] = hv[i] / s;
    }
    double R0[3][3];
    for (int i = 0; i < 3; ++i)
        for (int j = 0; j < 3; ++j)
            R0[i][j] = Vs[i][0] * U[j][0] + Vs[i][1] * U[j][1] + Vs[i][2] * U[j][2];
    const double det =
        R0[0][0] * (R0[1][1] * R0[2][2] - R0[1][2] * R0[2][1])
      - R0[0][1] * (R0[1][0] * R0[2][2] - R0[1][2] * R0[2][0])
      + R0[0][2] * (R0[1][0] * R0[2][1] - R0[1][1] * R0[2][0]);
    const double dsg = (det < 0.0) ? -1.0 : 1.0;
    double R[3][3];
    for (int i = 0; i < 3; ++i)
        for (int j = 0; j < 3; ++j)
            R[i][j] = Vs[i][0] * U[j][0] + Vs[i][1] * U[j][1] + dsg * Vs[i][2] * U[j][2];
    for (int i = 0; i < 3; ++i)
        for (int j = 0; j < 3; ++j)
            out[b * 9 + i * 3 + j] = (float)R[i][j];
    for (int i = 0; i < 3; ++i) {
        const double ti = -(R[i][0] * mus[0] + R[i][1] * mus[1] + R[i][2] * mus[2]) + muc[i];
        out[NB * 9 + b * 3 + i] = (float)ti;
    }
}

// ---------------------------------------------------------------------------
// Fused kernel: p = exp(temp*QK^T/sqrt(dk)); corr = (sum p*tgt)/(sum p);
// 15 per-batch moments via f64 atomics; last block per batch runs Kabsch.
//
// Split-bf16 (hi/lo truncation) x 3 MFMA => fp32-quality dots.
// 256 blocks (1/CU), 8 waves 2(n)x4(m), wave tile 64x32, m-tile pairing.
// T14 async-STAGE: step s+1's global loads issued before step s's compute
// barrier -> HBM latency hides under the ds_read+MFMA phase.
// ---------------------------------------------------------------------------
__global__ __launch_bounds__(512, 2) void attn_moments_mfma(
    const float* __restrict__ src_emb,
    const float* __restrict__ tgt_emb,
    const float* __restrict__ src_pts,
    const float* __restrict__ tgt_pts,
    const float* __restrict__ temperature,
    double* __restrict__ moments,
    int* __restrict__ counters,
    float* __restrict__ out)
{
    __shared__ short Qhi[BN * BK];        // 16 KB
    __shared__ short Qlo[BN * BK];        // 16 KB
    __shared__ short Khi[2][BM * BK];     // 32 KB
    __shared__ short Klo[2][BM * BK];     // 32 KB
    __shared__ float cw[8][4][16][4];     // 8 KB: [wave][g][fr*4+i][quant]

    const int bid = blockIdx.x;
    const int b = bid >> 4;
    const int nt = bid & 15;
    const int n0 = nt * BN;

    const int tid = threadIdx.x;
    const int lane = tid & 63;
    const int wv = tid >> 6;
    const int wn = (wv >> 2) * 64;
    const int wm = (wv & 3) * 32;
    const int g = lane >> 4;
    const int r15 = lane & 15;

    const float c2 = temperature[b] * (0.044194173824159216f * 1.4426950408889634f);

    float den[4][4], nx[4][4], ny[4][4], nz[4][4];
#pragma unroll
    for (int fr = 0; fr < 4; ++fr)
#pragma unroll
        for (int i = 0; i < 4; ++i) { den[fr][i] = 0.f; nx[fr][i] = 0.f; ny[fr][i] = 0.f; nz[fr][i] = 0.f; }

    const int kg = wv;
    const int srow = lane * 2;
    const size_t ebase = (size_t)b * DKC * NP;
    const float* gq = src_emb + ebase + n0 + srow;
    const float* gk = tgt_emb + ebase + srow;
    const size_t pb3 = (size_t)b * 3 * NP;

    // in-flight staging registers: 3 tiles x 8 float2 (step s+1 prefetch)
    float2 V[3][8];
    auto issue_loads = [&](int s) {
        const int kb = (s & 7) * BK;
        const int mo = (s >> 3) * (2 * BM);
        const float* g0 = gq + (size_t)(kb + kg * 8) * NP;
        const float* g1 = gk + mo + (size_t)(kb + kg * 8) * NP;
#pragma unroll
        for (int j = 0; j < 8; ++j) {
            V[0][j] = *(const float2*)(g0 + (size_t)j * NP);
            V[1][j] = *(const float2*)(g1 + (size_t)j * NP);
            V[2][j] = *(const float2*)(g1 + BM + (size_t)j * NP);
        }
    };
    // swizzle: unit = row*8 + (kg ^ (row&7) ^ ((row>>3)&7)); 16B units.
    auto cvt_write = [&]() {
#pragma unroll
        for (int t = 0; t < 3; ++t) {
            short* dhi = (t == 0) ? Qhi : Khi[t - 1];
            short* dlo = (t == 0) ? Qlo : Klo[t - 1];
#pragma unroll
            for (int r = 0; r < 2; ++r) {
                const int row = srow + r;
                sh8 H, L;
#pragma unroll
                for (int j = 0; j < 8; ++j) {
                    const float x = (r == 0) ? V[t][j].x : V[t][j].y;
                    const unsigned u = __float_as_uint(x);
                    const float lof = x - __uint_as_float(u & 0xffff0000u);
                    H[j] = (short)(u >> 16);
                    L[j] = (short)(__float_as_uint(lof) >> 16);
                }
                const int unit = row * 8 + (kg ^ (row & 7) ^ ((row >> 3) & 7));
                *(sh8*)(dhi + unit * 8) = H;
                *(sh8*)(dlo + unit * 8) = L;
            }
        }
    };

    f32x4 acc[2][4][2];
    issue_loads(0);

    for (int s = 0; s < NSTEP; ++s) {
        const int kc = s & 7;
        if (kc == 0) {
#pragma unroll
            for (int t = 0; t < 2; ++t)
#pragma unroll
                for (int fr = 0; fr < 4; ++fr)
#pragma unroll
                    for (int mf = 0; mf < 2; ++mf) acc[t][fr][mf] = (f32x4)(0.f);
        }
        __syncthreads();            // all waves done reading LDS of step s-1
        cvt_write();                // consume V (vmcnt wait here), fill LDS
        if (s + 1 < NSTEP) issue_loads(s + 1);   // prefetch; in flight across compute
        __syncthreads();            // LDS ready

#pragma unroll
        for (int ks = 0; ks < 2; ++ks) {
            const int slot = ks * 4 + g;
            sh8 ah[4], al[4];
#pragma unroll
            for (int fr = 0; fr < 4; ++fr) {
                const int ar = wn + fr * 16 + r15;
                const int unit = ar * 8 + (slot ^ (ar & 7) ^ ((ar >> 3) & 7));
                ah[fr] = *(const sh8*)(Qhi + unit * 8);
                al[fr] = *(const sh8*)(Qlo + unit * 8);
            }
#pragma unroll
            for (int t = 0; t < 2; ++t) {
                sh8 bh[2], bl[2];
#pragma unroll
                for (int mf = 0; mf < 2; ++mf) {
                    const int br = wm + mf * 16 + r15;
                    const int unit = br * 8 + (slot ^ (br & 7) ^ ((br >> 3) & 7));
                    bh[mf] = *(const sh8*)(Khi[t] + unit * 8);
                    bl[mf] = *(const sh8*)(Klo[t] + unit * 8);
                }
#pragma unroll
                for (int fr = 0; fr < 4; ++fr)
#pragma unroll
                    for (int mf = 0; mf < 2; ++mf) {
                        acc[t][fr][mf] = __builtin_amdgcn_mfma_f32_16x16x32_bf16(ah[fr], bh[mf], acc[t][fr][mf], 0, 0, 0);
                        acc[t][fr][mf] = __builtin_amdgcn_mfma_f32_16x16x32_bf16(ah[fr], bl[mf], acc[t][fr][mf], 0, 0, 0);
                        acc[t][fr][mf] = __builtin_amdgcn_mfma_f32_16x16x32_bf16(al[fr], bh[mf], acc[t][fr][mf], 0, 0, 0);
                    }
            }
        }

        if (kc == 7) {
            // epilogue for m-pair pt = s>>3
            const int m0 = (s >> 3) * (2 * BM);
#pragma unroll
            for (int t = 0; t < 2; ++t)
#pragma unroll
                for (int mf = 0; mf < 2; ++mf) {
                    const int mc = m0 + t * BM + wm + mf * 16 + r15;  // D col = lane&15
                    const float t0 = tgt_pts[pb3 + mc];
                    const float t1 = tgt_pts[pb3 + NP + mc];
                    const float t2 = tgt_pts[pb3 + 2 * NP + mc];
#pragma unroll
                    for (int fr = 0; fr < 4; ++fr)
#pragma unroll
                        for (int i = 0; i < 4; ++i) {
                            const float p = exp2f(c2 * acc[t][fr][mf][i]);
                            den[fr][i] += p;
                            nx[fr][i] += p * t0;
                            ny[fr][i] += p * t1;
                            nz[fr][i] += p * t2;
                        }
                }
        }
    }

    // ---- step 1: intra-wave reduce over 16 lanes of each column group
#pragma unroll
    for (int fr = 0; fr < 4; ++fr)
#pragma unroll
        for (int i = 0; i < 4; ++i) {
#pragma unroll
            for (int off = 1; off <= 8; off <<= 1) {
                den[fr][i] += __shfl_xor(den[fr][i], off);
                nx[fr][i] += __shfl_xor(nx[fr][i], off);
                ny[fr][i] += __shfl_xor(ny[fr][i], off);
                nz[fr][i] += __shfl_xor(nz[fr][i], off);
            }
        }

    // ---- step 2: park wave partials in LDS
    __syncthreads();
    if (r15 == 0) {
#pragma unroll
        for (int fr = 0; fr < 4; ++fr)
#pragma unroll
            for (int i = 0; i < 4; ++i) {
                cw[wv][g][fr * 4 + i][0] = den[fr][i];
                cw[wv][g][fr * 4 + i][1] = nx[fr][i];
                cw[wv][g][fr * 4 + i][2] = ny[fr][i];
                cw[wv][g][fr * 4 + i][3] = nz[fr][i];
            }
    }
    __syncthreads();

    // ---- step 3: combine the 4 wm-waves; 128 threads own one n-row each
    if (tid < 128) {
        const int r = tid;
        const int wnIdx = r >> 6;
        const int fi = ((r >> 4) & 3) * 4 + (r & 3);
        const int gg = (r >> 2) & 3;
        float D = 0.f, X = 0.f, Y = 0.f, Z = 0.f;
#pragma unroll
        for (int w = 0; w < 4; ++w) {
            const int wave = wnIdx * 4 + w;
            D += cw[wave][gg][fi][0];
            X += cw[wave][gg][fi][1];
            Y += cw[wave][gg][fi][2];
            Z += cw[wave][gg][fi][3];
        }
        const int n = n0 + r;
        const double inv = 1.0 / (double)D;
        const double c0 = (double)X * inv;
        const double c1 = (double)Y * inv;
        const double c2d = (double)Z * inv;
        const double s0 = (double)src_pts[pb3 + n];
        const double s1 = (double)src_pts[pb3 + NP + n];
        const double s2 = (double)src_pts[pb3 + 2 * NP + n];
        double m15[15];
        m15[0] = s0;  m15[1] = s1;  m15[2] = s2;
        m15[3] = c0;  m15[4] = c1;  m15[5] = c2d;
        m15[6] = s0 * c0;  m15[7] = s0 * c1;  m15[8] = s0 * c2d;
        m15[9] = s1 * c0;  m15[10] = s1 * c1; m15[11] = s1 * c2d;
        m15[12] = s2 * c0; m15[13] = s2 * c1; m15[14] = s2 * c2d;
#pragma unroll
        for (int q = 0; q < 15; ++q)
#pragma unroll
            for (int off = 1; off <= 32; off <<= 1)
                m15[q] += __shfl_xor(m15[q], off);
        if ((tid & 63) == 0) {
            double* mb = moments + b * 15;
#pragma unroll
            for (int q = 0; q < 15; ++q) atomicAdd(&mb[q], m15[q]);
        }
    }

    // ---- step 4: last block of this batch runs Kabsch inline
    __syncthreads();   // drains the moment atomics (vmcnt(0) before barrier)
    if (tid == 0) {
        __threadfence();
        const int prev = __hip_atomic_fetch_add(&counters[b], 1, __ATOMIC_ACQ_REL,
                                                __HIP_MEMORY_SCOPE_AGENT);
        if (prev == 15 - 1 + 1 - 1 + 1) { /* == 15 */ }
        if (prev == 15) {
            double a[15];
            const double* mb = moments + b * 15;
#pragma unroll
            for (int q = 0; q < 15; ++q)
                a[q] = __hip_atomic_load(&mb[q], __ATOMIC_ACQUIRE, __HIP_MEMORY_SCOPE_AGENT);
            kabsch_body(a, out, b);
        }
    }
}

extern "C" void kernel_launch(void* const* d_in, const int* in_sizes, int n_in,
                              void* d_out, int out_size, void* d_ws, size_t ws_size,
                              hipStream_t stream)
{
    const float* src_emb = (const float*)d_in[0];
    const float* tgt_emb = (const float*)d_in[1];
    const float* src_pts = (const float*)d_in[2];
    const float* tgt_pts = (const float*)d_in[3];
    const float* temp    = (const float*)d_in[4];
    float* out = (float*)d_out;
    double* moments = (double*)d_ws;                       // 16*15 doubles = 1920 B
    int* counters = (int*)((char*)d_ws + NB * 15 * sizeof(double));  // 16 ints

    hipMemsetAsync(d_ws, 0, NB * 15 * sizeof(double) + NB * sizeof(int), stream);
    attn_moments_mfma<<<dim3(NB * 16), dim3(512), 0, stream>>>(
        src_emb, tgt_emb, src_pts, tgt_pts, temp, moments, counters, out);
}